// Round 2
// 144.120 us; speedup vs baseline: 1.0823x; 1.0823x over previous
//
#include <hip/hip_runtime.h>

// GraphSAGE 2-layer: N=50000, D=128, DEG=16.
// R4 (resubmit after infra failure): fragment-packed weights (coalesced bfrag
// loads), packed f32x2 mean accumulation (v_pk_add_f32 path), 32-bit
// byte-offset gather addressing.
typedef __attribute__((ext_vector_type(8))) short short8;
typedef __attribute__((ext_vector_type(4))) float f32x4;
typedef __attribute__((ext_vector_type(2))) float f32x2;

#define N_NODES 50000
#define D 128
#define DEG 16
#define K2 256   // 2*D
#define BM 32    // rows per block

static __device__ __forceinline__ unsigned short f2b(float f) {
    union { float f; unsigned int u; } v; v.f = f;
    return (unsigned short)((v.u + 0x7fffu + ((v.u >> 16) & 1u)) >> 16);
}

// ---- prep ----
// blocks 0..31: pack W1,W2 (stored (K2, D) row-major) into MFMA-fragment order:
//   o = w*8192 + kk*1024 + ct*512 + lane*8 + e
//   maps to W[k][n], k = kk*32 + (lane>>4)*8 + e, n = w*32 + ct*16 + (lane&15)
// so sage's per-(kk,ct) fragment load is 64 lanes * 16B fully contiguous.
// blocks 32..: x -> bf16.
__global__ void prep(const float* __restrict__ x, unsigned short* __restrict__ xb,
                     const float* __restrict__ W1, const float* __restrict__ W2,
                     unsigned short* __restrict__ Wf1, unsigned short* __restrict__ Wf2) {
    int b = blockIdx.x;
    if (b < 32) {
        int o  = (b * 256 + threadIdx.x) * 4;   // 0..32764, writes coalesced
        int e0 = o & 7;                         // 0 or 4
        int l  = (o >> 3) & 63;
        int ct = (o >> 9) & 1;
        int kk = (o >> 10) & 7;
        int w  = o >> 13;
        int n  = w * 32 + ct * 16 + (l & 15);
        int kb = kk * 32 + (l >> 4) * 8 + e0;
        ushort4 a, c;
        a.x = f2b(W1[(kb + 0) * D + n]);
        a.y = f2b(W1[(kb + 1) * D + n]);
        a.z = f2b(W1[(kb + 2) * D + n]);
        a.w = f2b(W1[(kb + 3) * D + n]);
        *(ushort4*)(Wf1 + o) = a;
        c.x = f2b(W2[(kb + 0) * D + n]);
        c.y = f2b(W2[(kb + 1) * D + n]);
        c.z = f2b(W2[(kb + 2) * D + n]);
        c.w = f2b(W2[(kb + 3) * D + n]);
        *(ushort4*)(Wf2 + o) = c;
    } else {
        int i = ((b - 32) * 256 + threadIdx.x) * 4;
        if (i < N_NODES * D) {
            float4 v = *(const float4*)(x + i);
            ushort4 o4;
            o4.x = f2b(v.x); o4.y = f2b(v.y); o4.z = f2b(v.z); o4.w = f2b(v.w);
            *(ushort4*)(xb + i) = o4;
        }
    }
}

// ---- fused layer: out = relu( [feat | mean_nbr(feat)] @ W + b ) ----
template <int OUT_BF16>
__global__ __launch_bounds__(256, 4)
void sage_layer(const unsigned short* __restrict__ feat,  // N x D bf16
                const int* __restrict__ nbr,              // N x DEG
                const unsigned short* __restrict__ wf,    // fragment-packed bf16
                const float* __restrict__ bias,           // D f32
                void* __restrict__ out)
{
    __shared__ __align__(16) unsigned short Hl[BM * 264];  // A tile, row stride 264
    __shared__ int Nl[BM * DEG];                           // 512 neighbor ids
    const int tid  = threadIdx.x;
    const int row0 = blockIdx.x * BM;

    // stage neighbor indices (512 ints)
    if (tid < 128) {
        int g = row0 * DEG + tid * 4;
        int gmax = N_NODES * DEG - 4;
        if (g > gmax) g = gmax;              // tail clamp; extra rows unused
        *(int4*)(Nl + tid * 4) = *(const int4*)(nbr + g);
    }
    __syncthreads();

    const char* fb = (const char*)feat;      // byte base: row = id*256B

    // ---- gather: 2 (row, 8-dim-slice) pairs per thread; 16 loads in flight each
    #pragma unroll
    for (int p = 0; p < 2; ++p) {
        int a = tid + p * 256;
        int r = a >> 4;                      // 0..31
        int s = a & 15;                      // 8-dim slice
        int grow = row0 + r;
        if (grow >= N_NODES) grow = N_NODES - 1;
        unsigned sB = (unsigned)s * 16u;
        short8 self = *(const short8*)(fb + (unsigned)grow * 256u + sB);

        int4 i0 = *(const int4*)(Nl + r * 16);
        int4 i1 = *(const int4*)(Nl + r * 16 + 4);
        int4 i2 = *(const int4*)(Nl + r * 16 + 8);
        int4 i3 = *(const int4*)(Nl + r * 16 + 12);
        int ids[16] = { i0.x, i0.y, i0.z, i0.w, i1.x, i1.y, i1.z, i1.w,
                        i2.x, i2.y, i2.z, i2.w, i3.x, i3.y, i3.z, i3.w };

        short8 v[16];
        #pragma unroll
        for (int j = 0; j < 16; ++j)
            v[j] = *(const short8*)(fb + (((unsigned)ids[j]) << 8) + sB);

        // packed bf16->f32 + f32x2 accumulate (v_pk_add_f32 path)
        f32x2 am[4];
        #pragma unroll
        for (int i = 0; i < 4; ++i) am[i] = (f32x2){0.f, 0.f};
        #pragma unroll
        for (int j = 0; j < 16; ++j) {
            union { short8 s8; unsigned u[4]; } vv; vv.s8 = v[j];
            #pragma unroll
            for (int i = 0; i < 4; ++i) {
                unsigned ui = vv.u[i];
                f32x2 e;
                e.x = __uint_as_float(ui << 16);          // low bf16 (dim 2i)
                e.y = __uint_as_float(ui & 0xffff0000u);  // high bf16 (dim 2i+1)
                am[i] += e;
            }
        }

        unsigned short* hr = Hl + r * 264 + s * 8;
        *(short8*)(hr) = self;
        union { unsigned short u[8]; short8 s8; } m;
        #pragma unroll
        for (int i = 0; i < 4; ++i) {
            m.u[2 * i]     = f2b(am[i].x * 0.0625f);
            m.u[2 * i + 1] = f2b(am[i].y * 0.0625f);
        }
        *(short8*)(hr + D) = m.s8;
    }

    // ---- B fragments (fragment-packed: 64 lanes x 16B contiguous per load)
    const int lane = tid & 63;
    const int w    = tid >> 6;
    const int quad = lane >> 4;
    const int l16  = lane & 15;
    const int n_base = w * 32;
    const unsigned short* wfw = wf + w * 8192;
    short8 bfrag[8][2];
    #pragma unroll
    for (int kk = 0; kk < 8; ++kk)
        #pragma unroll
        for (int ct = 0; ct < 2; ++ct)
            bfrag[kk][ct] = *(const short8*)(wfw + kk * 1024 + ct * 512 + lane * 8);

    __syncthreads();

    // ---- MFMA: 32 rows (2 rt) x 32 cols (2 ct) per wave
    f32x4 acc[2][2];
    #pragma unroll
    for (int rt = 0; rt < 2; ++rt)
        #pragma unroll
        for (int ct = 0; ct < 2; ++ct)
            acc[rt][ct] = (f32x4){0.f, 0.f, 0.f, 0.f};

    #pragma unroll
    for (int kk = 0; kk < 8; ++kk) {
        short8 afrag[2];
        #pragma unroll
        for (int rt = 0; rt < 2; ++rt)
            afrag[rt] = *(const short8*)(&Hl[(rt * 16 + l16) * 264 + kk * 32 + quad * 8]);
        #pragma unroll
        for (int rt = 0; rt < 2; ++rt)
            #pragma unroll
            for (int ct = 0; ct < 2; ++ct)
                acc[rt][ct] = __builtin_amdgcn_mfma_f32_16x16x32_bf16(
                    afrag[rt], bfrag[kk][ct], acc[rt][ct], 0, 0, 0);
    }

    // ---- epilogue
    float bv0 = bias[n_base + l16];
    float bv1 = bias[n_base + 16 + l16];
    #pragma unroll
    for (int rt = 0; rt < 2; ++rt) {
        int grow_base = row0 + rt * 16 + quad * 4;
        #pragma unroll
        for (int r = 0; r < 4; ++r) {
            int grow = grow_base + r;
            if (grow >= N_NODES) continue;
            #pragma unroll
            for (int ct = 0; ct < 2; ++ct) {
                float vv = acc[rt][ct][r] + (ct ? bv1 : bv0);
                vv = vv > 0.f ? vv : 0.f;
                int col = n_base + ct * 16 + l16;
                if (OUT_BF16)
                    ((unsigned short*)out)[grow * D + col] = f2b(vv);
                else
                    ((float*)out)[grow * D + col] = vv;
            }
        }
    }
}

extern "C" void kernel_launch(void* const* d_in, const int* in_sizes, int n_in,
                              void* d_out, int out_size, void* d_ws, size_t ws_size,
                              hipStream_t stream) {
    const float* x  = (const float*)d_in[0];
    const int*   nb = (const int*)d_in[1];
    const float* W1 = (const float*)d_in[2];
    const float* b1 = (const float*)d_in[3];
    const float* W2 = (const float*)d_in[4];
    const float* b2 = (const float*)d_in[5];

    char* ws = (char*)d_ws;
    unsigned short* Wf1 = (unsigned short*)(ws);
    unsigned short* Wf2 = (unsigned short*)(ws + 65536);
    unsigned short* xb  = (unsigned short*)(ws + 131072);              // N x D bf16
    unsigned short* h1  = (unsigned short*)(ws + 131072 + 12800000);   // N x D bf16

    prep<<<32 + 6250, 256, 0, stream>>>(x, xb, W1, W2, Wf1, Wf2);

    const int mgrid = (N_NODES + BM - 1) / BM;  // 1563
    sage_layer<1><<<mgrid, 256, 0, stream>>>(xb, nb, Wf1, b1, h1);
    sage_layer<0><<<mgrid, 256, 0, stream>>>(h1, nb, Wf2, b2, d_out);
}